// Round 8
// baseline (322.107 us; speedup 1.0000x reference)
//
#include <hip/hip_runtime.h>
#include <math.h>

#define SEQ 4096
#define DM  1024

#define BM 128
#define BN 128
#define NCT (SEQ / BN)   // 32 column tiles
#define KS 32            // K per MFMA step

typedef __attribute__((ext_vector_type(8))) short bf16x8;
typedef __attribute__((ext_vector_type(4))) float f32x4;

union U4 { uint4 u; unsigned short s[8]; };

__device__ __forceinline__ float bf2f(unsigned short u) {
    return __uint_as_float(((unsigned int)u) << 16);
}
__device__ __forceinline__ unsigned short f2bf(float f) {
    unsigned int u = __float_as_uint(f);
    return (unsigned short)((u + 0x7FFFu + ((u >> 16) & 1u)) >> 16);
}

// Decide whether buffer holds packed bf16 (1) or fp32 (0).
__device__ __forceinline__ int detect_bf16(const void* p0) {
    const unsigned int* p = (const unsigned int*)p0;
    int cnt = 0;
    #pragma unroll
    for (int i = 0; i < 64; i++) {
        unsigned int e = (p[i] >> 7) & 0xFFu;
        cnt += (e >= 112u && e <= 140u) ? 1 : 0;
    }
    return cnt >= 48 ? 1 : 0;
}

// load 8 consecutive elements (element index idx, multiple of 8) as fp32
__device__ __forceinline__ void load8(const void* base, size_t idx, int isbf, float* v) {
    if (isbf) {
        U4 t; t.u = *(const uint4*)((const unsigned short*)base + idx);
        #pragma unroll
        for (int q = 0; q < 8; q++) v[q] = bf2f(t.s[q]);
    } else {
        const float* f = (const float*)base + idx;
        float4 a = *(const float4*)f;
        float4 b = *(const float4*)(f + 4);
        v[0] = a.x; v[1] = a.y; v[2] = a.z; v[3] = a.w;
        v[4] = b.x; v[5] = b.y; v[6] = b.z; v[7] = b.w;
    }
}

// async global -> LDS, 16 bytes per lane (linear LDS dest: base + lane*16)
__device__ __forceinline__ void gl16(const void* g, void* l) {
    __builtin_amdgcn_global_load_lds(
        (const __attribute__((address_space(1))) unsigned int*)g,
        (__attribute__((address_space(3))) unsigned int*)l, 16, 0, 0);
}

// ---------------- split3: x / wq / wk -> exact bf16 hi/lo pairs, one pass.
__global__ __launch_bounds__(256)
void split3_kernel(const void* __restrict__ X, const void* __restrict__ Wq,
                   const void* __restrict__ Wk,
                   unsigned short* __restrict__ Xhi, unsigned short* __restrict__ Xlo,
                   unsigned short* __restrict__ Wqhi, unsigned short* __restrict__ Wqlo,
                   unsigned short* __restrict__ Wkhi, unsigned short* __restrict__ Wklo)
{
    const int b = blockIdx.x;
    const void* src;
    unsigned short *Hi, *Lo;
    size_t i;
    if (b < 2048)      { src = X;  Hi = Xhi;  Lo = Xlo;  i = ((size_t)b * 256 + threadIdx.x) * 8; }
    else if (b < 2560) { src = Wq; Hi = Wqhi; Lo = Wqlo; i = ((size_t)(b - 2048) * 256 + threadIdx.x) * 8; }
    else               { src = Wk; Hi = Wkhi; Lo = Wklo; i = ((size_t)(b - 2560) * 256 + threadIdx.x) * 8; }
    const int isbf = detect_bf16(src);
    float v[8];
    load8(src, i, isbf, v);
    U4 h, l;
    #pragma unroll
    for (int q = 0; q < 8; q++) {
        h.s[q] = f2bf(v[q]);
        l.s[q] = f2bf(v[q] - bf2f(h.s[q]));
    }
    *(uint4*)(Hi + i) = h.u;
    *(uint4*)(Lo + i) = l.u;
}

// ---------------- generic NT split-bf16 MFMA partial GEMM (4-term, fp32-grade):
// O[kz*pstride + m*DM + n] = scale * sum_{k in chunk kz} A[m,k]*B[n,k]
// Hi streams staged via global_load_lds (XOR-swizzled source, linear LDS);
// LO STREAMS ARE LOADED PER-LANE DIRECT FROM GLOBAL (r5 proved the loop is
// staging-bound, not MFMA-bound: each 16B lo-fragment has only 2-wave reuse,
// so LDS round-trip is overhead; direct loads drain under the same barrier
// vmcnt(0)). Halves staged bytes and LDS (32->16KB).
__global__ __launch_bounds__(256)
void part_mfma_kernel(const unsigned short* __restrict__ Ahi, const unsigned short* __restrict__ Alo,
                      const unsigned short* __restrict__ Bhi, const unsigned short* __restrict__ Blo,
                      float* __restrict__ O, int kchunk, size_t pstride, float scale)
{
    __shared__ unsigned short lAhi[128 * KS];
    __shared__ unsigned short lBhi[128 * KS];

    const int t = threadIdx.x;
    // XCD-aware bijective remap (T1)
    const int gy  = gridDim.y;
    const int nwg = 8 * gy * gridDim.z;
    const int lid = (blockIdx.z * gy + blockIdx.y) * 8 + blockIdx.x;
    const int swz = (lid & 7) * (nwg >> 3) + (lid >> 3);
    const int bx  = swz & 7;
    const int rst = swz >> 3;
    const int by  = rst % gy;
    const int kz  = rst / gy;

    const int lane = t & 63;
    const int w    = t >> 6;
    const int wr   = w >> 1;
    const int wc   = w & 1;
    const int fr   = lane & 15;
    const int fq   = lane >> 4;

    f32x4 acc[4][4];
    #pragma unroll
    for (int i = 0; i < 4; i++)
        #pragma unroll
        for (int j = 0; j < 4; j++)
            acc[i][j] = (f32x4){0.f, 0.f, 0.f, 0.f};

    const int trow = t >> 2;
    const int tcs  = t & 3;
    const int k0   = kz * kchunk;

    for (int kt = k0; kt < k0 + kchunk; kt += KS) {
        #pragma unroll
        for (int p = 0; p < 2; p++) {
            const int row = p * 64 + trow;
            const int sc  = tcs ^ ((row >> 1) & 3);
            const int lof = (p * 256 + t) * 16;
            const size_t ga = (size_t)(by * BM + row) * DM + kt + sc * 8;
            const size_t gb = (size_t)(bx * BN + row) * DM + kt + sc * 8;
            gl16(Ahi + ga, (char*)lAhi + lof);
            gl16(Bhi + gb, (char*)lBhi + lof);
        }
        // direct per-lane lo-fragment loads (swizzle cancels: chunk = fq)
        bf16x8 al[4], bl[4];
        #pragma unroll
        for (int mi = 0; mi < 4; mi++) {
            const int ar_ = wr * 64 + mi * 16 + fr;
            al[mi] = *(const bf16x8*)(Alo + (size_t)(by * BM + ar_) * DM + kt + fq * 8);
        }
        #pragma unroll
        for (int nj = 0; nj < 4; nj++) {
            const int br = wc * 64 + nj * 16 + fr;
            bl[nj] = *(const bf16x8*)(Blo + (size_t)(bx * BN + br) * DM + kt + fq * 8);
        }
        __syncthreads();

        bf16x8 bh[4];
        #pragma unroll
        for (int nj = 0; nj < 4; nj++) {
            const int br = wc * 64 + nj * 16 + fr;
            const int bc = fq ^ ((br >> 1) & 3);
            bh[nj] = *(const bf16x8*)&lBhi[br * KS + bc * 8];
        }
        #pragma unroll
        for (int mi = 0; mi < 4; mi++) {
            const int ar_ = wr * 64 + mi * 16 + fr;
            const int ac_ = fq ^ ((ar_ >> 1) & 3);
            bf16x8 ah = *(const bf16x8*)&lAhi[ar_ * KS + ac_ * 8];
            #pragma unroll
            for (int nj = 0; nj < 4; nj++) {
                acc[mi][nj] = __builtin_amdgcn_mfma_f32_16x16x32_bf16(ah, bh[nj], acc[mi][nj], 0, 0, 0);
                acc[mi][nj] = __builtin_amdgcn_mfma_f32_16x16x32_bf16(al[mi], bh[nj], acc[mi][nj], 0, 0, 0);
                acc[mi][nj] = __builtin_amdgcn_mfma_f32_16x16x32_bf16(ah, bl[nj], acc[mi][nj], 0, 0, 0);
                acc[mi][nj] = __builtin_amdgcn_mfma_f32_16x16x32_bf16(al[mi], bl[nj], acc[mi][nj], 0, 0, 0);
            }
        }
        __syncthreads();
    }

    float* Op = O + (size_t)kz * pstride;
    #pragma unroll
    for (int mi = 0; mi < 4; mi++)
        #pragma unroll
        for (int reg = 0; reg < 4; reg++) {
            const int row = by * BM + wr * 64 + mi * 16 + fq * 4 + reg;
            #pragma unroll
            for (int nj = 0; nj < 4; nj++) {
                const int col = bx * BN + wc * 64 + nj * 16 + fr;
                Op[(size_t)row * DM + col] = acc[mi][nj][reg] * scale;
            }
        }
}

// ---------------- W2T = sum of 4 K-chunk partials -> bf16 hi/lo split
__global__ __launch_bounds__(256)
void w2_reduce_split_kernel(const float* __restrict__ P, unsigned short* __restrict__ Hi,
                            unsigned short* __restrict__ Lo)
{
    const size_t N = (size_t)DM * DM;
    size_t i = ((size_t)blockIdx.x * 256 + threadIdx.x) * 8;
    float v[8];
    #pragma unroll
    for (int h = 0; h < 8; h += 4) {
        float4 a = *(const float4*)(P + i + h);
        float4 b = *(const float4*)(P + N + i + h);
        float4 c = *(const float4*)(P + 2 * N + i + h);
        float4 d = *(const float4*)(P + 3 * N + i + h);
        v[h + 0] = a.x + b.x + c.x + d.x;
        v[h + 1] = a.y + b.y + c.y + d.y;
        v[h + 2] = a.z + b.z + c.z + d.z;
        v[h + 3] = a.w + b.w + c.w + d.w;
    }
    U4 h, l;
    #pragma unroll
    for (int q = 0; q < 8; q++) {
        h.s[q] = f2bf(v[q]);
        l.s[q] = f2bf(v[q] - bf2f(h.s[q]));
    }
    *(uint4*)(Hi + i) = h.u;
    *(uint4*)(Lo + i) = l.u;
}

// ---------------- QW = P0 + P1, split into bf16 hi/lo pair (for scores A operand)
__global__ __launch_bounds__(256)
void qw_combine_split_kernel(const float* __restrict__ P0, const float* __restrict__ P1,
                             unsigned short* __restrict__ Hi, unsigned short* __restrict__ Lo)
{
    size_t i = ((size_t)blockIdx.x * 256 + threadIdx.x) * 8;
    float4 a0 = *(const float4*)(P0 + i);
    float4 a1 = *(const float4*)(P0 + i + 4);
    float4 b0 = *(const float4*)(P1 + i);
    float4 b1 = *(const float4*)(P1 + i + 4);
    float v[8] = {a0.x + b0.x, a0.y + b0.y, a0.z + b0.z, a0.w + b0.w,
                  a1.x + b1.x, a1.y + b1.y, a1.z + b1.z, a1.w + b1.w};
    U4 h, l;
    #pragma unroll
    for (int q = 0; q < 8; q++) {
        h.s[q] = f2bf(v[q]);
        l.s[q] = f2bf(v[q] - bf2f(h.s[q]));
    }
    *(uint4*)(Hi + i) = h.u;
    *(uint4*)(Lo + i) = l.u;
}

// ---------------- scores via MFMA: S = (QWhi+QWlo) @ X^T, fused softmax partials.
// Hi streams via LDS; QWlo per-lane direct from global (same rationale as
// part_mfma). Plain launch bounds (r6's (256,4) cap spilled: 2.3x regression).
// No XCD swizzle (r4: FETCH 82->139MB, dur flat).
__global__ __launch_bounds__(256)
void scores_mfma_kernel(const unsigned short* __restrict__ QWhi,
                        const unsigned short* __restrict__ QWlo,
                        const void* __restrict__ X,
                        float* __restrict__ pm, float* __restrict__ pl,
                        void* __restrict__ out)
{
    __shared__ unsigned short lAhi[128 * KS];
    __shared__ unsigned short lBhi[128 * KS];
    __shared__ unsigned short lBlo[128 * KS];   // fp32-X path only
    __shared__ float smax[128][2];
    __shared__ float ssum[128][2];

    const int isbf = detect_bf16(X);
    const int t    = threadIdx.x;
    const int bx   = blockIdx.x;   // col tile
    const int by   = blockIdx.y;   // row tile
    const int lane = t & 63;
    const int w    = t >> 6;
    const int wr   = w >> 1;
    const int wc   = w & 1;
    const int fr   = lane & 15;
    const int fq   = lane >> 4;

    f32x4 acc[4][4];
    #pragma unroll
    for (int i = 0; i < 4; i++)
        #pragma unroll
        for (int j = 0; j < 4; j++)
            acc[i][j] = (f32x4){0.f, 0.f, 0.f, 0.f};

    const int trow = t >> 2;
    const int tcs  = t & 3;

    for (int kt = 0; kt < DM; kt += KS) {
        #pragma unroll
        for (int p = 0; p < 2; p++) {
            const int row = p * 64 + trow;
            const int sc  = tcs ^ ((row >> 1) & 3);
            const int lof = (p * 256 + t) * 16;
            const size_t ga = (size_t)(by * BM + row) * DM + kt + sc * 8;
            gl16(QWhi + ga, (char*)lAhi + lof);
            if (isbf) {
                const size_t gb = (size_t)(bx * BN + row) * DM + kt + sc * 8;
                gl16((const unsigned short*)X + gb, (char*)lBhi + lof);
            }
        }
        // direct per-lane A-lo fragments (swizzle cancels: chunk = fq)
        bf16x8 al[4];
        #pragma unroll
        for (int mi = 0; mi < 4; mi++) {
            const int ar_ = wr * 64 + mi * 16 + fr;
            al[mi] = *(const bf16x8*)(QWlo + (size_t)(by * BM + ar_) * DM + kt + fq * 8);
        }
        if (!isbf) {
            const int row  = t >> 1;
            const int half = t & 1;
            const float* xp = (const float*)X + (size_t)(bx * BN + row) * DM + kt + half * 16;
            float4 v0 = ((const float4*)xp)[0];
            float4 v1 = ((const float4*)xp)[1];
            float4 v2 = ((const float4*)xp)[2];
            float4 v3 = ((const float4*)xp)[3];
            float vv[16] = {v0.x, v0.y, v0.z, v0.w, v1.x, v1.y, v1.z, v1.w,
                            v2.x, v2.y, v2.z, v2.w, v3.x, v3.y, v3.z, v3.w};
            U4 h0, h1, l0, l1;
            #pragma unroll
            for (int q = 0; q < 8; q++) {
                h0.s[q] = f2bf(vv[q]);
                l0.s[q] = f2bf(vv[q] - bf2f(h0.s[q]));
                h1.s[q] = f2bf(vv[8 + q]);
                l1.s[q] = f2bf(vv[8 + q] - bf2f(h1.s[q]));
            }
            const int s  = (row >> 1) & 3;
            const int ca = (2 * half) ^ s;
            const int cb = (2 * half + 1) ^ s;
            *(uint4*)&lBhi[row * KS + ca * 8] = h0.u;
            *(uint4*)&lBhi[row * KS + cb * 8] = h1.u;
            *(uint4*)&lBlo[row * KS + ca * 8] = l0.u;
            *(uint4*)&lBlo[row * KS + cb * 8] = l1.u;
        }
        __syncthreads();

        bf16x8 bh[4];
        #pragma unroll
        for (int nj = 0; nj < 4; nj++) {
            const int br = wc * 64 + nj * 16 + fr;
            const int bc = fq ^ ((br >> 1) & 3);
            bh[nj] = *(const bf16x8*)&lBhi[br * KS + bc * 8];
        }
        #pragma unroll
        for (int mi = 0; mi < 4; mi++) {
            const int ar_ = wr * 64 + mi * 16 + fr;
            const int ac_ = fq ^ ((ar_ >> 1) & 3);
            bf16x8 ah = *(const bf16x8*)&lAhi[ar_ * KS + ac_ * 8];
            #pragma unroll
            for (int nj = 0; nj < 4; nj++) {
                acc[mi][nj] = __builtin_amdgcn_mfma_f32_16x16x32_bf16(ah, bh[nj], acc[mi][nj], 0, 0, 0);
                acc[mi][nj] = __builtin_amdgcn_mfma_f32_16x16x32_bf16(al[mi], bh[nj], acc[mi][nj], 0, 0, 0);
            }
        }
        if (!isbf) {
            bf16x8 bl[4];
            #pragma unroll
            for (int nj = 0; nj < 4; nj++) {
                const int br = wc * 64 + nj * 16 + fr;
                const int bc = fq ^ ((br >> 1) & 3);
                bl[nj] = *(const bf16x8*)&lBlo[br * KS + bc * 8];
            }
            #pragma unroll
            for (int mi = 0; mi < 4; mi++) {
                const int ar_ = wr * 64 + mi * 16 + fr;
                const int ac_ = fq ^ ((ar_ >> 1) & 3);
                bf16x8 ah = *(const bf16x8*)&lAhi[ar_ * KS + ac_ * 8];
                #pragma unroll
                for (int nj = 0; nj < 4; nj++)
                    acc[mi][nj] = __builtin_amdgcn_mfma_f32_16x16x32_bf16(ah, bl[nj], acc[mi][nj], 0, 0, 0);
            }
        }
        __syncthreads();
    }

    // ---- fused softmax epilogue ----
    float rmx[4][4];
    #pragma unroll
    for (int mi = 0; mi < 4; mi++)
        #pragma unroll
        for (int reg = 0; reg < 4; reg++) {
            float m = acc[mi][0][reg];
            #pragma unroll
            for (int nj = 1; nj < 4; nj++) m = fmaxf(m, acc[mi][nj][reg]);
            m = fmaxf(m, __shfl_xor(m, 1, 64));
            m = fmaxf(m, __shfl_xor(m, 2, 64));
            m = fmaxf(m, __shfl_xor(m, 4, 64));
            m = fmaxf(m, __shfl_xor(m, 8, 64));
            rmx[mi][reg] = m;
        }
    if (fr == 0) {
        #pragma unroll
        for (int mi = 0; mi < 4; mi++)
            #pragma unroll
            for (int reg = 0; reg < 4; reg++)
                smax[wr * 64 + mi * 16 + fq * 4 + reg][wc] = rmx[mi][reg];
    }
    __syncthreads();
    float mt[4][4];
    #pragma unroll
    for (int mi = 0; mi < 4; mi++)
        #pragma unroll
        for (int reg = 0; reg < 4; reg++) {
            const int r = wr * 64 + mi * 16 + fq * 4 + reg;
            mt[mi][reg] = fmaxf(smax[r][0], smax[r][1]);
        }
    float rsm[4][4];
    #pragma unroll
    for (int mi = 0; mi < 4; mi++)
        #pragma unroll
        for (int reg = 0; reg < 4; reg++) rsm[mi][reg] = 0.f;
    #pragma unroll
    for (int mi = 0; mi < 4; mi++)
        #pragma unroll
        for (int nj = 0; nj < 4; nj++)
            #pragma unroll
            for (int reg = 0; reg < 4; reg++) {
                float e = __expf(acc[mi][nj][reg] - mt[mi][reg]);
                acc[mi][nj][reg] = e;
                rsm[mi][reg] += e;
            }
    #pragma unroll
    for (int mi = 0; mi < 4; mi++)
        #pragma unroll
        for (int reg = 0; reg < 4; reg++) {
            float s = rsm[mi][reg];
            s += __shfl_xor(s, 1, 64);
            s += __shfl_xor(s, 2, 64);
            s += __shfl_xor(s, 4, 64);
            s += __shfl_xor(s, 8, 64);
            if (fr == 0) ssum[wr * 64 + mi * 16 + fq * 4 + reg][wc] = s;
        }
    // store P = exp(S - m_tile)
    #pragma unroll
    for (int mi = 0; mi < 4; mi++)
        #pragma unroll
        for (int reg = 0; reg < 4; reg++) {
            const int row = by * BM + wr * 64 + mi * 16 + fq * 4 + reg;
            #pragma unroll
            for (int nj = 0; nj < 4; nj++) {
                const int col = bx * BN + wc * 64 + nj * 16 + fr;
                const float v = acc[mi][nj][reg];
                if (isbf)
                    ((unsigned short*)out)[(size_t)row * SEQ + col] = f2bf(v);
                else
                    ((float*)out)[(size_t)row * SEQ + col] = v;
            }
        }
    __syncthreads();
    if (t < 128) {
        const int grow = by * BM + t;
        pm[(size_t)bx * SEQ + grow] = fmaxf(smax[t][0], smax[t][1]);
        pl[(size_t)bx * SEQ + grow] = ssum[t][0] + ssum[t][1];
    }
}

// ---------------- fixup (reduce folded in): each block owns half of one output
// row; it computes the row's global (m, l) from raw pm/pl partials (shuffle
// reduce in wave 0), then applies out *= exp(m_tile - m)/l.
__global__ __launch_bounds__(256)
void fixup_kernel(const float* __restrict__ pm, const float* __restrict__ pl,
                  const void* __restrict__ X, void* __restrict__ out)
{
    __shared__ float sm, sl;
    const int row = blockIdx.x >> 1;            // 2 blocks per row
    const int t   = threadIdx.x;

    if (t < 64) {
        float mv = (t < NCT) ? pm[(size_t)t * SEQ + row] : -3.4e38f;
        float m = mv;
        m = fmaxf(m, __shfl_xor(m, 1, 64));
        m = fmaxf(m, __shfl_xor(m, 2, 64));
        m = fmaxf(m, __shfl_xor(m, 4, 64));
        m = fmaxf(m, __shfl_xor(m, 8, 64));
        m = fmaxf(m, __shfl_xor(m, 16, 64));
        m = fmaxf(m, __shfl_xor(m, 32, 64));
        float lv = (t < NCT) ? pl[(size_t)t * SEQ + row] * __expf(mv - m) : 0.f;
        lv += __shfl_xor(lv, 1, 64);
        lv += __shfl_xor(lv, 2, 64);
        lv += __shfl_xor(lv, 4, 64);
        lv += __shfl_xor(lv, 8, 64);
        lv += __shfl_xor(lv, 16, 64);
        lv += __shfl_xor(lv, 32, 64);
        if (t == 0) { sm = m; sl = lv; }
    }
    __syncthreads();
    const float m  = sm;
    const float il = 1.f / sl;

    const int isbf = detect_bf16(X);
    const size_t g = ((size_t)blockIdx.x * 256 + t) * 8;   // element index
    const int col  = (int)(g & (SEQ - 1));
    const float f  = __expf(pm[(size_t)(col >> 7) * SEQ + row] - m) * il;
    if (isbf) {
        unsigned short* p = (unsigned short*)out + g;
        U4 v; v.u = *(const uint4*)p;
        #pragma unroll
        for (int q = 0; q < 8; q++) v.s[q] = f2bf(bf2f(v.s[q]) * f);
        *(uint4*)p = v.u;
    } else {
        float* p = (float*)out + g;
        float4 a = *(const float4*)p;
        float4 b = *(const float4*)(p + 4);
        a.x *= f; a.y *= f; a.z *= f; a.w *= f;
        b.x *= f; b.y *= f; b.z *= f; b.w *= f;
        *(float4*)p = a;
        *(float4*)(p + 4) = b;
    }
}

extern "C" void kernel_launch(void* const* d_in, const int* in_sizes, int n_in,
                              void* d_out, int out_size, void* d_ws, size_t ws_size,
                              hipStream_t stream)
{
    const void* x  = d_in[0];
    const void* wq = d_in[1];
    const void* wk = d_in[2];
    // d_in[3] (w_v), d_in[4] (out_proj) unused by the reference output.

    // Buffer timeline (ws = 32 MiB, d_out = scratch until scores):
    //   phase          ws[0,8M)  ws[8,16M)  ws[16,20M)   ws[16,17M)  d_out
    //   1 split3       Xhi<-     Xlo<-      -            -           W splits<- [0,8M)
    //   2 w2t mfma     (Xhi)     (Xlo)      -            -           ->W reads; W2P<- [8,24M)
    //   3 w2_red_split (Xhi)     (Xlo)      W2Thi/lo<-   -           ->W2P read
    //   4 qw mfma      ->read    ->read     ->read       -           QP0/QP1<- [24,56M)
    //   5 qw_combine   QWhi<-    QWlo<-     -            -           ->QP read
    //   6 scores       ->read    ->read     (dead)       pm/pl<-     P<- [0,64M)
    //   7 fixup        -         -          -            pm/pl read  P r/w
    char* wsb = (char*)d_ws;
    char* dob = (char*)d_out;
    unsigned short* Xhi   = (unsigned short*)wsb;
    unsigned short* Xlo   = (unsigned short*)(wsb + ((size_t)8 << 20));
    unsigned short* QWhi  = (unsigned short*)wsb;                       // over dead Xhi
    unsigned short* QWlo  = (unsigned short*)(wsb + ((size_t)8 << 20)); // over dead Xlo
    unsigned short* W2Thi = (unsigned short*)(wsb + ((size_t)16 << 20));
    unsigned short* W2Tlo = (unsigned short*)(wsb + ((size_t)18 << 20));
    float*          pm    = (float*)(wsb + ((size_t)16 << 20));         // over dead W2T
    float*          pl    = pm + (size_t)NCT * SEQ;

    unsigned short* Wkhi = (unsigned short*)dob;
    unsigned short* Wklo = (unsigned short*)(dob + ((size_t)2 << 20));
    unsigned short* Wqhi = (unsigned short*)(dob + ((size_t)4 << 20));
    unsigned short* Wqlo = (unsigned short*)(dob + ((size_t)6 << 20));
    float*          W2P  = (float*)(dob + ((size_t)8 << 20));   // 4 x 4MB partials
    float*          QP0  = (float*)(dob + ((size_t)24 << 20));  // 16MB
    float*          QP1  = QP0 + (size_t)SEQ * DM;              // 16MB

    dim3 blk(256);
    // 1. x, wq, wk -> bf16 hi/lo splits (one pass)
    split3_kernel<<<dim3(3072), blk, 0, stream>>>(x, wq, wk, Xhi, Xlo, Wqhi, Wqlo, Wkhi, Wklo);
    // 2. W2T = (1/32) * wk @ wq^T via 4-term split MFMA, split-K=4 (grid 8x8x4)
    part_mfma_kernel<<<dim3(8, DM / BM, 4), blk, 0, stream>>>(
        Wkhi, Wklo, Wqhi, Wqlo, W2P, DM / 4, (size_t)DM * DM, 0.03125f);
    // 3. sum partials -> W2T bf16 hi/lo
    w2_reduce_split_kernel<<<dim3(DM * DM / (8 * 256)), blk, 0, stream>>>(W2P, W2Thi, W2Tlo);
    // 4. QW = Xs @ W2T^T via 4-term split MFMA, split-K=2 (grid 8x32x2)
    part_mfma_kernel<<<dim3(8, SEQ / BM, 2), blk, 0, stream>>>(
        Xhi, Xlo, W2Thi, W2Tlo, QP0, DM / 2, (size_t)SEQ * DM, 1.0f);
    // 5. QW partial sum -> bf16 hi/lo
    qw_combine_split_kernel<<<dim3(SEQ * DM / (8 * 256)), blk, 0, stream>>>(QP0, QP1, QWhi, QWlo);
    // 6. scores via MFMA + fused softmax partials, P to d_out
    scores_mfma_kernel<<<dim3(SEQ / BN, SEQ / BM), blk, 0, stream>>>(QWhi, QWlo, x, pm, pl, d_out);
    // 7. fixup (reduce folded in): out *= exp(m_tile - m)/l
    fixup_kernel<<<dim3(SEQ * SEQ / (8 * 256)), blk, 0, stream>>>(pm, pl, x, d_out);
}

// Round 9
// 299.875 us; speedup vs baseline: 1.0741x; 1.0741x over previous
//
#include <hip/hip_runtime.h>
#include <math.h>

#define SEQ 4096
#define DM  1024

#define BM 128
#define BN 128
#define NCT (SEQ / BN)   // 32 column tiles
#define KS 32            // K per MFMA step

typedef __attribute__((ext_vector_type(8))) short bf16x8;
typedef __attribute__((ext_vector_type(4))) float f32x4;

union U4 { uint4 u; unsigned short s[8]; };

__device__ __forceinline__ float bf2f(unsigned short u) {
    return __uint_as_float(((unsigned int)u) << 16);
}
__device__ __forceinline__ unsigned short f2bf(float f) {
    unsigned int u = __float_as_uint(f);
    return (unsigned short)((u + 0x7FFFu + ((u >> 16) & 1u)) >> 16);
}

// Decide whether buffer holds packed bf16 (1) or fp32 (0).
__device__ __forceinline__ int detect_bf16(const void* p0) {
    const unsigned int* p = (const unsigned int*)p0;
    int cnt = 0;
    #pragma unroll
    for (int i = 0; i < 64; i++) {
        unsigned int e = (p[i] >> 7) & 0xFFu;
        cnt += (e >= 112u && e <= 140u) ? 1 : 0;
    }
    return cnt >= 48 ? 1 : 0;
}

// load 8 consecutive elements (element index idx, multiple of 8) as fp32
__device__ __forceinline__ void load8(const void* base, size_t idx, int isbf, float* v) {
    if (isbf) {
        U4 t; t.u = *(const uint4*)((const unsigned short*)base + idx);
        #pragma unroll
        for (int q = 0; q < 8; q++) v[q] = bf2f(t.s[q]);
    } else {
        const float* f = (const float*)base + idx;
        float4 a = *(const float4*)f;
        float4 b = *(const float4*)(f + 4);
        v[0] = a.x; v[1] = a.y; v[2] = a.z; v[3] = a.w;
        v[4] = b.x; v[5] = b.y; v[6] = b.z; v[7] = b.w;
    }
}

// async global -> LDS, 16 bytes per lane (linear LDS dest: base + lane*16)
__device__ __forceinline__ void gl16(const void* g, void* l) {
    __builtin_amdgcn_global_load_lds(
        (const __attribute__((address_space(1))) unsigned int*)g,
        (__attribute__((address_space(3))) unsigned int*)l, 16, 0, 0);
}

// ---------------- split3: x / wq / wk -> exact bf16 hi/lo pairs, one pass.
__global__ __launch_bounds__(256)
void split3_kernel(const void* __restrict__ X, const void* __restrict__ Wq,
                   const void* __restrict__ Wk,
                   unsigned short* __restrict__ Xhi, unsigned short* __restrict__ Xlo,
                   unsigned short* __restrict__ Wqhi, unsigned short* __restrict__ Wqlo,
                   unsigned short* __restrict__ Wkhi, unsigned short* __restrict__ Wklo)
{
    const int b = blockIdx.x;
    const void* src;
    unsigned short *Hi, *Lo;
    size_t i;
    if (b < 2048)      { src = X;  Hi = Xhi;  Lo = Xlo;  i = ((size_t)b * 256 + threadIdx.x) * 8; }
    else if (b < 2560) { src = Wq; Hi = Wqhi; Lo = Wqlo; i = ((size_t)(b - 2048) * 256 + threadIdx.x) * 8; }
    else               { src = Wk; Hi = Wkhi; Lo = Wklo; i = ((size_t)(b - 2560) * 256 + threadIdx.x) * 8; }
    const int isbf = detect_bf16(src);
    float v[8];
    load8(src, i, isbf, v);
    U4 h, l;
    #pragma unroll
    for (int q = 0; q < 8; q++) {
        h.s[q] = f2bf(v[q]);
        l.s[q] = f2bf(v[q] - bf2f(h.s[q]));
    }
    *(uint4*)(Hi + i) = h.u;
    *(uint4*)(Lo + i) = l.u;
}

// ---------------- generic NT split-bf16 MFMA partial GEMM (4-term, fp32-grade):
// O[kz*pstride + m*DM + n] = scale * sum_{k in chunk kz} A[m,k]*B[n,k]
// All four streams staged via global_load_lds (coalesced 1KB/instr). r8 proved
// per-lane direct lo-loads regress (uncoalesced: 16B fragments at 2KB row
// stride scatter across cache lines, inflating the vmcnt drain). 4-term kept:
// r5 proved the loop staging-bound (3-term cut time-neutral, cost accuracy).
__global__ __launch_bounds__(256)
void part_mfma_kernel(const unsigned short* __restrict__ Ahi, const unsigned short* __restrict__ Alo,
                      const unsigned short* __restrict__ Bhi, const unsigned short* __restrict__ Blo,
                      float* __restrict__ O, int kchunk, size_t pstride, float scale)
{
    __shared__ unsigned short lAhi[128 * KS];
    __shared__ unsigned short lAlo[128 * KS];
    __shared__ unsigned short lBhi[128 * KS];
    __shared__ unsigned short lBlo[128 * KS];

    const int t = threadIdx.x;
    // XCD-aware bijective remap (T1)
    const int gy  = gridDim.y;
    const int nwg = 8 * gy * gridDim.z;
    const int lid = (blockIdx.z * gy + blockIdx.y) * 8 + blockIdx.x;
    const int swz = (lid & 7) * (nwg >> 3) + (lid >> 3);
    const int bx  = swz & 7;
    const int rst = swz >> 3;
    const int by  = rst % gy;
    const int kz  = rst / gy;

    const int lane = t & 63;
    const int w    = t >> 6;
    const int wr   = w >> 1;
    const int wc   = w & 1;
    const int fr   = lane & 15;
    const int fq   = lane >> 4;

    f32x4 acc[4][4];
    #pragma unroll
    for (int i = 0; i < 4; i++)
        #pragma unroll
        for (int j = 0; j < 4; j++)
            acc[i][j] = (f32x4){0.f, 0.f, 0.f, 0.f};

    const int trow = t >> 2;
    const int tcs  = t & 3;
    const int k0   = kz * kchunk;

    for (int kt = k0; kt < k0 + kchunk; kt += KS) {
        #pragma unroll
        for (int p = 0; p < 2; p++) {
            const int row = p * 64 + trow;
            const int sc  = tcs ^ ((row >> 1) & 3);
            const int lof = (p * 256 + t) * 16;
            const size_t ga = (size_t)(by * BM + row) * DM + kt + sc * 8;
            const size_t gb = (size_t)(bx * BN + row) * DM + kt + sc * 8;
            gl16(Ahi + ga, (char*)lAhi + lof);
            gl16(Alo + ga, (char*)lAlo + lof);
            gl16(Bhi + gb, (char*)lBhi + lof);
            gl16(Blo + gb, (char*)lBlo + lof);
        }
        __syncthreads();

        bf16x8 bh[4], bl[4];
        #pragma unroll
        for (int nj = 0; nj < 4; nj++) {
            const int br = wc * 64 + nj * 16 + fr;
            const int bc = fq ^ ((br >> 1) & 3);
            bh[nj] = *(const bf16x8*)&lBhi[br * KS + bc * 8];
            bl[nj] = *(const bf16x8*)&lBlo[br * KS + bc * 8];
        }
        #pragma unroll
        for (int mi = 0; mi < 4; mi++) {
            const int ar_ = wr * 64 + mi * 16 + fr;
            const int ac_ = fq ^ ((ar_ >> 1) & 3);
            bf16x8 ah = *(const bf16x8*)&lAhi[ar_ * KS + ac_ * 8];
            bf16x8 al = *(const bf16x8*)&lAlo[ar_ * KS + ac_ * 8];
            #pragma unroll
            for (int nj = 0; nj < 4; nj++) {
                acc[mi][nj] = __builtin_amdgcn_mfma_f32_16x16x32_bf16(ah, bh[nj], acc[mi][nj], 0, 0, 0);
                acc[mi][nj] = __builtin_amdgcn_mfma_f32_16x16x32_bf16(al, bh[nj], acc[mi][nj], 0, 0, 0);
                acc[mi][nj] = __builtin_amdgcn_mfma_f32_16x16x32_bf16(ah, bl[nj], acc[mi][nj], 0, 0, 0);
                acc[mi][nj] = __builtin_amdgcn_mfma_f32_16x16x32_bf16(al, bl[nj], acc[mi][nj], 0, 0, 0);
            }
        }
        __syncthreads();
    }

    float* Op = O + (size_t)kz * pstride;
    #pragma unroll
    for (int mi = 0; mi < 4; mi++)
        #pragma unroll
        for (int reg = 0; reg < 4; reg++) {
            const int row = by * BM + wr * 64 + mi * 16 + fq * 4 + reg;
            #pragma unroll
            for (int nj = 0; nj < 4; nj++) {
                const int col = bx * BN + wc * 64 + nj * 16 + fr;
                Op[(size_t)row * DM + col] = acc[mi][nj][reg] * scale;
            }
        }
}

// ---------------- W2T = sum of 4 K-chunk partials -> bf16 hi/lo split
__global__ __launch_bounds__(256)
void w2_reduce_split_kernel(const float* __restrict__ P, unsigned short* __restrict__ Hi,
                            unsigned short* __restrict__ Lo)
{
    const size_t N = (size_t)DM * DM;
    size_t i = ((size_t)blockIdx.x * 256 + threadIdx.x) * 8;
    float v[8];
    #pragma unroll
    for (int h = 0; h < 8; h += 4) {
        float4 a = *(const float4*)(P + i + h);
        float4 b = *(const float4*)(P + N + i + h);
        float4 c = *(const float4*)(P + 2 * N + i + h);
        float4 d = *(const float4*)(P + 3 * N + i + h);
        v[h + 0] = a.x + b.x + c.x + d.x;
        v[h + 1] = a.y + b.y + c.y + d.y;
        v[h + 2] = a.z + b.z + c.z + d.z;
        v[h + 3] = a.w + b.w + c.w + d.w;
    }
    U4 h, l;
    #pragma unroll
    for (int q = 0; q < 8; q++) {
        h.s[q] = f2bf(v[q]);
        l.s[q] = f2bf(v[q] - bf2f(h.s[q]));
    }
    *(uint4*)(Hi + i) = h.u;
    *(uint4*)(Lo + i) = l.u;
}

// ---------------- QW = P0 + P1, split into bf16 hi/lo pair (for scores A operand)
__global__ __launch_bounds__(256)
void qw_combine_split_kernel(const float* __restrict__ P0, const float* __restrict__ P1,
                             unsigned short* __restrict__ Hi, unsigned short* __restrict__ Lo)
{
    size_t i = ((size_t)blockIdx.x * 256 + threadIdx.x) * 8;
    float4 a0 = *(const float4*)(P0 + i);
    float4 a1 = *(const float4*)(P0 + i + 4);
    float4 b0 = *(const float4*)(P1 + i);
    float4 b1 = *(const float4*)(P1 + i + 4);
    float v[8] = {a0.x + b0.x, a0.y + b0.y, a0.z + b0.z, a0.w + b0.w,
                  a1.x + b1.x, a1.y + b1.y, a1.z + b1.z, a1.w + b1.w};
    U4 h, l;
    #pragma unroll
    for (int q = 0; q < 8; q++) {
        h.s[q] = f2bf(v[q]);
        l.s[q] = f2bf(v[q] - bf2f(h.s[q]));
    }
    *(uint4*)(Hi + i) = h.u;
    *(uint4*)(Lo + i) = l.u;
}

// ---------------- scores via MFMA: S = (QWhi+QWlo) @ X^T, fused softmax partials.
// R4/R5/R7-proven config: plain launch bounds (VGPR ~92; r6's (256,4) cap
// spilled the accumulator: 2.3x regression), no XCD swizzle (r4: FETCH
// 82->139MB, dur flat), all streams LDS-staged (r8: direct-lo regressed).
__global__ __launch_bounds__(256)
void scores_mfma_kernel(const unsigned short* __restrict__ QWhi,
                        const unsigned short* __restrict__ QWlo,
                        const void* __restrict__ X,
                        float* __restrict__ pm, float* __restrict__ pl,
                        void* __restrict__ out)
{
    __shared__ unsigned short lAhi[128 * KS];
    __shared__ unsigned short lAlo[128 * KS];
    __shared__ unsigned short lBhi[128 * KS];
    __shared__ unsigned short lBlo[128 * KS];
    __shared__ float smax[128][2];
    __shared__ float ssum[128][2];

    const int isbf = detect_bf16(X);
    const int t    = threadIdx.x;
    const int bx   = blockIdx.x;   // col tile
    const int by   = blockIdx.y;   // row tile
    const int lane = t & 63;
    const int w    = t >> 6;
    const int wr   = w >> 1;
    const int wc   = w & 1;
    const int fr   = lane & 15;
    const int fq   = lane >> 4;

    f32x4 acc[4][4];
    #pragma unroll
    for (int i = 0; i < 4; i++)
        #pragma unroll
        for (int j = 0; j < 4; j++)
            acc[i][j] = (f32x4){0.f, 0.f, 0.f, 0.f};

    const int trow = t >> 2;
    const int tcs  = t & 3;

    for (int kt = 0; kt < DM; kt += KS) {
        #pragma unroll
        for (int p = 0; p < 2; p++) {
            const int row = p * 64 + trow;
            const int sc  = tcs ^ ((row >> 1) & 3);
            const int lof = (p * 256 + t) * 16;
            const size_t ga = (size_t)(by * BM + row) * DM + kt + sc * 8;
            gl16(QWhi + ga, (char*)lAhi + lof);
            gl16(QWlo + ga, (char*)lAlo + lof);
            if (isbf) {
                const size_t gb = (size_t)(bx * BN + row) * DM + kt + sc * 8;
                gl16((const unsigned short*)X + gb, (char*)lBhi + lof);
            }
        }
        if (!isbf) {
            const int row  = t >> 1;
            const int half = t & 1;
            const float* xp = (const float*)X + (size_t)(bx * BN + row) * DM + kt + half * 16;
            float4 v0 = ((const float4*)xp)[0];
            float4 v1 = ((const float4*)xp)[1];
            float4 v2 = ((const float4*)xp)[2];
            float4 v3 = ((const float4*)xp)[3];
            float vv[16] = {v0.x, v0.y, v0.z, v0.w, v1.x, v1.y, v1.z, v1.w,
                            v2.x, v2.y, v2.z, v2.w, v3.x, v3.y, v3.z, v3.w};
            U4 h0, h1, l0, l1;
            #pragma unroll
            for (int q = 0; q < 8; q++) {
                h0.s[q] = f2bf(vv[q]);
                l0.s[q] = f2bf(vv[q] - bf2f(h0.s[q]));
                h1.s[q] = f2bf(vv[8 + q]);
                l1.s[q] = f2bf(vv[8 + q] - bf2f(h1.s[q]));
            }
            const int s  = (row >> 1) & 3;
            const int ca = (2 * half) ^ s;
            const int cb = (2 * half + 1) ^ s;
            *(uint4*)&lBhi[row * KS + ca * 8] = h0.u;
            *(uint4*)&lBhi[row * KS + cb * 8] = h1.u;
            *(uint4*)&lBlo[row * KS + ca * 8] = l0.u;
            *(uint4*)&lBlo[row * KS + cb * 8] = l1.u;
        }
        __syncthreads();

        bf16x8 bh[4];
        #pragma unroll
        for (int nj = 0; nj < 4; nj++) {
            const int br = wc * 64 + nj * 16 + fr;
            const int bc = fq ^ ((br >> 1) & 3);
            bh[nj] = *(const bf16x8*)&lBhi[br * KS + bc * 8];
        }
        #pragma unroll
        for (int mi = 0; mi < 4; mi++) {
            const int ar_ = wr * 64 + mi * 16 + fr;
            const int ac_ = fq ^ ((ar_ >> 1) & 3);
            bf16x8 ah = *(const bf16x8*)&lAhi[ar_ * KS + ac_ * 8];
            bf16x8 al = *(const bf16x8*)&lAlo[ar_ * KS + ac_ * 8];
            #pragma unroll
            for (int nj = 0; nj < 4; nj++) {
                acc[mi][nj] = __builtin_amdgcn_mfma_f32_16x16x32_bf16(ah, bh[nj], acc[mi][nj], 0, 0, 0);
                acc[mi][nj] = __builtin_amdgcn_mfma_f32_16x16x32_bf16(al, bh[nj], acc[mi][nj], 0, 0, 0);
            }
        }
        if (!isbf) {
            bf16x8 bl[4];
            #pragma unroll
            for (int nj = 0; nj < 4; nj++) {
                const int br = wc * 64 + nj * 16 + fr;
                const int bc = fq ^ ((br >> 1) & 3);
                bl[nj] = *(const bf16x8*)&lBlo[br * KS + bc * 8];
            }
            #pragma unroll
            for (int mi = 0; mi < 4; mi++) {
                const int ar_ = wr * 64 + mi * 16 + fr;
                const int ac_ = fq ^ ((ar_ >> 1) & 3);
                bf16x8 ah = *(const bf16x8*)&lAhi[ar_ * KS + ac_ * 8];
                #pragma unroll
                for (int nj = 0; nj < 4; nj++)
                    acc[mi][nj] = __builtin_amdgcn_mfma_f32_16x16x32_bf16(ah, bl[nj], acc[mi][nj], 0, 0, 0);
            }
        }
        __syncthreads();
    }

    // ---- fused softmax epilogue ----
    float rmx[4][4];
    #pragma unroll
    for (int mi = 0; mi < 4; mi++)
        #pragma unroll
        for (int reg = 0; reg < 4; reg++) {
            float m = acc[mi][0][reg];
            #pragma unroll
            for (int nj = 1; nj < 4; nj++) m = fmaxf(m, acc[mi][nj][reg]);
            m = fmaxf(m, __shfl_xor(m, 1, 64));
            m = fmaxf(m, __shfl_xor(m, 2, 64));
            m = fmaxf(m, __shfl_xor(m, 4, 64));
            m = fmaxf(m, __shfl_xor(m, 8, 64));
            rmx[mi][reg] = m;
        }
    if (fr == 0) {
        #pragma unroll
        for (int mi = 0; mi < 4; mi++)
            #pragma unroll
            for (int reg = 0; reg < 4; reg++)
                smax[wr * 64 + mi * 16 + fq * 4 + reg][wc] = rmx[mi][reg];
    }
    __syncthreads();
    float mt[4][4];
    #pragma unroll
    for (int mi = 0; mi < 4; mi++)
        #pragma unroll
        for (int reg = 0; reg < 4; reg++) {
            const int r = wr * 64 + mi * 16 + fq * 4 + reg;
            mt[mi][reg] = fmaxf(smax[r][0], smax[r][1]);
        }
    float rsm[4][4];
    #pragma unroll
    for (int mi = 0; mi < 4; mi++)
        #pragma unroll
        for (int reg = 0; reg < 4; reg++) rsm[mi][reg] = 0.f;
    #pragma unroll
    for (int mi = 0; mi < 4; mi++)
        #pragma unroll
        for (int nj = 0; nj < 4; nj++)
            #pragma unroll
            for (int reg = 0; reg < 4; reg++) {
                float e = __expf(acc[mi][nj][reg] - mt[mi][reg]);
                acc[mi][nj][reg] = e;
                rsm[mi][reg] += e;
            }
    #pragma unroll
    for (int mi = 0; mi < 4; mi++)
        #pragma unroll
        for (int reg = 0; reg < 4; reg++) {
            float s = rsm[mi][reg];
            s += __shfl_xor(s, 1, 64);
            s += __shfl_xor(s, 2, 64);
            s += __shfl_xor(s, 4, 64);
            s += __shfl_xor(s, 8, 64);
            if (fr == 0) ssum[wr * 64 + mi * 16 + fq * 4 + reg][wc] = s;
        }
    // store P = exp(S - m_tile)
    #pragma unroll
    for (int mi = 0; mi < 4; mi++)
        #pragma unroll
        for (int reg = 0; reg < 4; reg++) {
            const int row = by * BM + wr * 64 + mi * 16 + fq * 4 + reg;
            #pragma unroll
            for (int nj = 0; nj < 4; nj++) {
                const int col = bx * BN + wc * 64 + nj * 16 + fr;
                const float v = acc[mi][nj][reg];
                if (isbf)
                    ((unsigned short*)out)[(size_t)row * SEQ + col] = f2bf(v);
                else
                    ((float*)out)[(size_t)row * SEQ + col] = v;
            }
        }
    __syncthreads();
    if (t < 128) {
        const int grow = by * BM + t;
        pm[(size_t)bx * SEQ + grow] = fmaxf(smax[t][0], smax[t][1]);
        pl[(size_t)bx * SEQ + grow] = ssum[t][0] + ssum[t][1];
    }
}

// ---------------- fixup (reduce folded in): each block owns half of one output
// row; it computes the row's global (m, l) from raw pm/pl partials (shuffle
// reduce in wave 0), then applies out *= exp(m_tile - m)/l.
__global__ __launch_bounds__(256)
void fixup_kernel(const float* __restrict__ pm, const float* __restrict__ pl,
                  const void* __restrict__ X, void* __restrict__ out)
{
    __shared__ float sm, sl;
    const int row = blockIdx.x >> 1;            // 2 blocks per row
    const int t   = threadIdx.x;

    if (t < 64) {
        float mv = (t < NCT) ? pm[(size_t)t * SEQ + row] : -3.4e38f;
        float m = mv;
        m = fmaxf(m, __shfl_xor(m, 1, 64));
        m = fmaxf(m, __shfl_xor(m, 2, 64));
        m = fmaxf(m, __shfl_xor(m, 4, 64));
        m = fmaxf(m, __shfl_xor(m, 8, 64));
        m = fmaxf(m, __shfl_xor(m, 16, 64));
        m = fmaxf(m, __shfl_xor(m, 32, 64));
        float lv = (t < NCT) ? pl[(size_t)t * SEQ + row] * __expf(mv - m) : 0.f;
        lv += __shfl_xor(lv, 1, 64);
        lv += __shfl_xor(lv, 2, 64);
        lv += __shfl_xor(lv, 4, 64);
        lv += __shfl_xor(lv, 8, 64);
        lv += __shfl_xor(lv, 16, 64);
        lv += __shfl_xor(lv, 32, 64);
        if (t == 0) { sm = m; sl = lv; }
    }
    __syncthreads();
    const float m  = sm;
    const float il = 1.f / sl;

    const int isbf = detect_bf16(X);
    const size_t g = ((size_t)blockIdx.x * 256 + t) * 8;   // element index
    const int col  = (int)(g & (SEQ - 1));
    const float f  = __expf(pm[(size_t)(col >> 7) * SEQ + row] - m) * il;
    if (isbf) {
        unsigned short* p = (unsigned short*)out + g;
        U4 v; v.u = *(const uint4*)p;
        #pragma unroll
        for (int q = 0; q < 8; q++) v.s[q] = f2bf(bf2f(v.s[q]) * f);
        *(uint4*)p = v.u;
    } else {
        float* p = (float*)out + g;
        float4 a = *(const float4*)p;
        float4 b = *(const float4*)(p + 4);
        a.x *= f; a.y *= f; a.z *= f; a.w *= f;
        b.x *= f; b.y *= f; b.z *= f; b.w *= f;
        *(float4*)p = a;
        *(float4*)(p + 4) = b;
    }
}

extern "C" void kernel_launch(void* const* d_in, const int* in_sizes, int n_in,
                              void* d_out, int out_size, void* d_ws, size_t ws_size,
                              hipStream_t stream)
{
    const void* x  = d_in[0];
    const void* wq = d_in[1];
    const void* wk = d_in[2];
    // d_in[3] (w_v), d_in[4] (out_proj) unused by the reference output.

    // Buffer timeline (ws = 32 MiB, d_out = scratch until scores):
    //   phase          ws[0,8M)  ws[8,16M)  ws[16,20M)   ws[16,17M)  d_out
    //   1 split3       Xhi<-     Xlo<-      -            -           W splits<- [0,8M)
    //   2 w2t mfma     (Xhi)     (Xlo)      -            -           ->W reads; W2P<- [8,24M)
    //   3 w2_red_split (Xhi)     (Xlo)      W2Thi/lo<-   -           ->W2P read
    //   4 qw mfma      ->read    ->read     ->read       -           QP0/QP1<- [24,56M)
    //   5 qw_combine   QWhi<-    QWlo<-     -            -           ->QP read
    //   6 scores       ->read    ->read     (dead)       pm/pl<-     P<- [0,64M)
    //   7 fixup        -         -          -            pm/pl read  P r/w
    char* wsb = (char*)d_ws;
    char* dob = (char*)d_out;
    unsigned short* Xhi   = (unsigned short*)wsb;
    unsigned short* Xlo   = (unsigned short*)(wsb + ((size_t)8 << 20));
    unsigned short* QWhi  = (unsigned short*)wsb;                       // over dead Xhi
    unsigned short* QWlo  = (unsigned short*)(wsb + ((size_t)8 << 20)); // over dead Xlo
    unsigned short* W2Thi = (unsigned short*)(wsb + ((size_t)16 << 20));
    unsigned short* W2Tlo = (unsigned short*)(wsb + ((size_t)18 << 20));
    float*          pm    = (float*)(wsb + ((size_t)16 << 20));         // over dead W2T
    float*          pl    = pm + (size_t)NCT * SEQ;

    unsigned short* Wkhi = (unsigned short*)dob;
    unsigned short* Wklo = (unsigned short*)(dob + ((size_t)2 << 20));
    unsigned short* Wqhi = (unsigned short*)(dob + ((size_t)4 << 20));
    unsigned short* Wqlo = (unsigned short*)(dob + ((size_t)6 << 20));
    float*          W2P  = (float*)(dob + ((size_t)8 << 20));   // 4 x 4MB partials
    float*          QP0  = (float*)(dob + ((size_t)24 << 20));  // 16MB
    float*          QP1  = QP0 + (size_t)SEQ * DM;              // 16MB

    dim3 blk(256);
    // 1. x, wq, wk -> bf16 hi/lo splits (one pass)
    split3_kernel<<<dim3(3072), blk, 0, stream>>>(x, wq, wk, Xhi, Xlo, Wqhi, Wqlo, Wkhi, Wklo);
    // 2. W2T = (1/32) * wk @ wq^T via 4-term split MFMA, split-K=4 (grid 8x8x4)
    part_mfma_kernel<<<dim3(8, DM / BM, 4), blk, 0, stream>>>(
        Wkhi, Wklo, Wqhi, Wqlo, W2P, DM / 4, (size_t)DM * DM, 0.03125f);
    // 3. sum partials -> W2T bf16 hi/lo
    w2_reduce_split_kernel<<<dim3(DM * DM / (8 * 256)), blk, 0, stream>>>(W2P, W2Thi, W2Tlo);
    // 4. QW = Xs @ W2T^T via 4-term split MFMA, split-K=2 (grid 8x32x2)
    part_mfma_kernel<<<dim3(8, SEQ / BM, 2), blk, 0, stream>>>(
        Xhi, Xlo, W2Thi, W2Tlo, QP0, DM / 2, (size_t)SEQ * DM, 1.0f);
    // 5. QW partial sum -> bf16 hi/lo
    qw_combine_split_kernel<<<dim3(SEQ * DM / (8 * 256)), blk, 0, stream>>>(QP0, QP1, QWhi, QWlo);
    // 6. scores via MFMA + fused softmax partials, P to d_out
    scores_mfma_kernel<<<dim3(SEQ / BN, SEQ / BM), blk, 0, stream>>>(QWhi, QWlo, x, pm, pl, d_out);
    // 7. fixup (reduce folded in): out *= exp(m_tile - m)/l
    fixup_kernel<<<dim3(SEQ * SEQ / (8 * 256)), blk, 0, stream>>>(pm, pl, x, d_out);
}